// Round 6
// baseline (20984.224 us; speedup 1.0000x reference)
//
#include <hip/hip_runtime.h>

// GRU: T=1024 B=64 D=256 H=512 O=256.
// Round 6: XCD-local communication. 128 WGs, 8 groups x 8 batch rows,
// group = blockIdx&7 (= XCD under round-robin dispatch). All 16 WGs of a
// group share one XCD's L2: producers store h_t (bf16) into hs[t] with plain
// stores; consumers poll hs[t-1] with sc0 (L1-bypass) loads validated by a
// canary (0xFFFF = bf16 -NaN, unreachable from finite GRU math; hs is a
// virgin-address ring so no ABA). Fallback for wrong XCD mapping: after 48
// fast rounds, escalate to hcG — R5's proven sc0sc1 IF ring (8 slots, LSB
// tag, producer-drained). Both paths deliver identical bf16 values.

#define T_ 1024
#define B_ 64
#define D_ 256
#define H_ 512
#define G_ 1536
#define O_ 256

typedef __attribute__((ext_vector_type(8))) short short8;
typedef __attribute__((ext_vector_type(4))) short short4v;
typedef __attribute__((ext_vector_type(4))) float float4v;
typedef __attribute__((ext_vector_type(4))) unsigned uint4v;

static __device__ __forceinline__ unsigned short f2b(float f) {
  unsigned u = __builtin_bit_cast(unsigned, f);
  u += 0x7fffu + ((u >> 16) & 1u);          // RNE (finite inputs)
  return (unsigned short)(u >> 16);
}

static __device__ __forceinline__ bool has_canary(uint4v d) {
  const unsigned m = 0xFFFFu;
  return ((d.x & m) == m) | ((d.x >> 16) == m) |
         ((d.y & m) == m) | ((d.y >> 16) == m) |
         ((d.z & m) == m) | ((d.z >> 16) == m) |
         ((d.w & m) == m) | ((d.w >> 16) == m);
}

// 16B sc0 (L2) load with the wait fused in-block (reg-use hazard fix from R5)
static __device__ __forceinline__ uint4v poll16_l2(const unsigned short* p) {
  uint4v d;
  asm volatile("global_load_dwordx4 %0, %1, off sc0\n\t"
               "s_waitcnt vmcnt(0)"
               : "=&v"(d) : "v"(p) : "memory");
  return d;
}

// escalation: read 8 tagged fp32 from hcG (IF), pack to 8 bf16 on success
static __device__ __forceinline__ bool try_esc(const float* gbase, int c,
                                               unsigned etag, uint4v& out) {
  const float* p = gbase + (size_t)(c >> 6) * 512 + (size_t)(c & 63) * 8;
  uint4v a, b;
  asm volatile("global_load_dwordx4 %0, %2, off sc0 sc1\n\t"
               "global_load_dwordx4 %1, %3, off sc0 sc1\n\t"
               "s_waitcnt vmcnt(0)"
               : "=&v"(a), "=&v"(b) : "v"(p), "v"(p + 4) : "memory");
  unsigned x = (a.x ^ etag) | (a.y ^ etag) | (a.z ^ etag) | (a.w ^ etag) |
               (b.x ^ etag) | (b.y ^ etag) | (b.z ^ etag) | (b.w ^ etag);
  if (x & 1u) return false;
  // producer stored (bf16<<16)|tag, so >>16 recovers the exact bf16
  out.x = (a.x >> 16) | (a.y & 0xFFFF0000u);
  out.y = (a.z >> 16) | (a.w & 0xFFFF0000u);
  out.z = (b.x >> 16) | (b.y & 0xFFFF0000u);
  out.w = (b.z >> 16) | (b.w & 0xFFFF0000u);
  return true;
}

// ---------------------------------------------------------------- prep ------
__global__ __launch_bounds__(256) void prep_kernel(
    const float* __restrict__ x, const float* __restrict__ Wi,
    const float* __restrict__ Wh, const float* __restrict__ Wo,
    unsigned short* __restrict__ xb, unsigned short* __restrict__ WhT,
    unsigned short* __restrict__ WiT, unsigned short* __restrict__ WoT,
    unsigned* __restrict__ hsD, unsigned* __restrict__ hcG)
{
  const size_t NXB = (size_t)T_ * B_ * D_;       // 16777216 shorts
  const size_t NWH = (size_t)G_ * H_;            // 786432
  const size_t NWI = (size_t)G_ * D_;            // 393216
  const size_t NWO = (size_t)O_ * H_;            // 131072
  const size_t NHS = (size_t)T_ * B_ * H_ / 2;   // 16777216 dwords (canary)
  const size_t NHG = 262144;                     // hcG dwords
  const size_t NTOT = NXB + NWH + NWI + NWO + NHS + NHG;
  size_t i = (size_t)blockIdx.x * blockDim.x + threadIdx.x;
  const size_t stride = (size_t)gridDim.x * blockDim.x;
  for (; i < NTOT; i += stride) {
    if (i < NXB) { xb[i] = f2b(x[i]); continue; }
    size_t j = i - NXB;
    if (j < NWH) { size_t g = j >> 9, k = j & 511; WhT[j] = f2b(Wh[k * G_ + g]); continue; }
    j -= NWH;
    if (j < NWI) { size_t g = j >> 8, k = j & 255; WiT[j] = f2b(Wi[k * G_ + g]); continue; }
    j -= NWI;
    if (j < NWO) { size_t o = j >> 9, k = j & 511; WoT[j] = f2b(Wo[k * O_ + o]); continue; }
    j -= NWO;
    if (j < NHS) { hsD[j] = 0xFFFFFFFFu; continue; }   // bf16 canary pairs
    j -= NHS;
    hcG[j] = 1u;                                        // LSB=1 != tag 0
  }
}

// ---------------------------------------------------------------- scan ------
// 128 WGs x 384 thr (6 waves). group = wg&7 (8 batch rows, XCD-resident under
// %8 round-robin), slice = wg>>3 (32 h-cols). wave -> (gk = wave%3, s = wave/3).
// Gate waves: gk==0 (2 waves; 2 rows x 1 col per lane). Stagers: gk!=0
// (4 waves = 256 thr; 2 16B-chunks each of the 8KB group h tile).
__global__ __launch_bounds__(384, 2) void scan_kernel(
    const unsigned short* __restrict__ xb,
    const unsigned short* __restrict__ WhT,
    const unsigned short* __restrict__ WiT,
    unsigned short* __restrict__ hs,
    float* __restrict__ hcG,
    const float* __restrict__ bi,
    const float* __restrict__ bhn,
    const float* __restrict__ h0)
{
  const int wg = blockIdx.x;
  const int group = wg & 7;                  // = XCD (heuristic, not relied on)
  const int slice = wg >> 3;                 // 0..15
  const int tid = threadIdx.x;
  const int wave = tid >> 6;
  const int lane = tid & 63;
  const int m = lane & 15;
  const int quad = lane >> 4;
  const int gk = wave % 3;
  const int s = wave / 3;
  const bool is_gate = (gk == 0);
  const int sid = is_gate ? 0 : ((((gk - 1) + s * 2) << 6) | lane);  // 0..255
  const int row0 = group * 8;
  const int jbase = slice * 32 + s * 16;
  const int gcol = gk * 512 + jbase + m;

  __shared__ unsigned short hT[16 * 512];   // bf16 A tile; rows 8..15 zero
  __shared__ float lds_h[6][256];
  __shared__ float lds_x[6][256];

  // persistent B fragments (registers)
  short8 Bh[16], Bx[8];
  {
    const unsigned short* p = WhT + (size_t)gcol * H_ + quad * 8;
#pragma unroll
    for (int k = 0; k < 16; ++k) Bh[k] = *(const short8*)(p + k * 32);
    const unsigned short* q = WiT + (size_t)gcol * D_ + quad * 8;
#pragma unroll
    for (int k = 0; k < 8; ++k) Bx[k] = *(const short8*)(q + k * 32);
  }

  // gate-lane mapping: 2 rows x 1 col per lane (8 rows x 16 cols per wave)
  const int col16 = lane & 15;
  const int rr = lane >> 4;                  // 0..3 -> rows rr*2, rr*2+1
  const int jcol = jbase + col16;
  const float bi_r = bi[jcol];
  const float bi_z = bi[512 + jcol];
  const float bi_n = bi[1024 + jcol];
  const float bhn_c = bhn[jcol];
  float hold[2];
#pragma unroll
  for (int i = 0; i < 2; ++i)
    hold[i] = h0[(size_t)(row0 + rr * 2 + i) * H_ + jcol];

  // x A-fragments for t=0 (rows clamped to the group's 8 rows)
  const int xrow = row0 + (m & 7);
  short8 xa[8];
  {
    const unsigned short* xp = xb + (size_t)xrow * D_ + quad * 8;
#pragma unroll
    for (int k = 0; k < 8; ++k) xa[k] = *(const short8*)(xp + k * 32);
  }

  // zero hT rows 8..15 once (A-operand padding)
  for (int i = tid; i < 2048; i += 384) ((unsigned*)hT)[2048 + i] = 0u;

  for (int t = 0; t < T_; ++t) {
    // ---- stage h_{t-1} -> hT (stager waves) ----
    if (!is_gate) {
      if (t == 0) {
        const float* src = h0 + (size_t)row0 * H_;
#pragma unroll
        for (int j = 0; j < 4; ++j) {
          const int c4 = sid + j * 256;            // 0..1023 fp32-x4 chunks
          const int r = c4 >> 7;
          const int q = c4 & 127;                  // col = q*4
          float4v d = *(const float4v*)(src + (size_t)r * H_ + q * 4);
          const int b2 = (q >> 1) ^ r;
          short4v o = { (short)f2b(d[0]), (short)f2b(d[1]),
                        (short)f2b(d[2]), (short)f2b(d[3]) };
          *(short4v*)&hT[(size_t)r * 512 + b2 * 8 + (q & 1) * 4] = o;
        }
      } else {
        const int tm1 = t - 1;
        const unsigned short* srcb = hs + ((size_t)tm1 * B_ + row0) * H_;
        const unsigned short* q0 = srcb + (size_t)sid * 8;
        const unsigned short* q1 = srcb + (size_t)(sid + 256) * 8;
        uint4v d0, d1;
        asm volatile("global_load_dwordx4 %0, %2, off sc0\n\t"
                     "global_load_dwordx4 %1, %3, off sc0\n\t"
                     "s_waitcnt vmcnt(0)"
                     : "=&v"(d0), "=&v"(d1) : "v"(q0), "v"(q1) : "memory");
        unsigned bad = (has_canary(d0) ? 1u : 0u) | (has_canary(d1) ? 2u : 0u);
        if (bad) {
          const unsigned etag = (unsigned)(tm1 >> 3) & 1u;
          const float* gbase = hcG + (size_t)((tm1 & 7) * 8 + group) * 4096;
          int rounds = 0;
          do {
            __builtin_amdgcn_s_sleep(1);
            if (++rounds <= 48) {                   // fast path: local L2
              if (bad & 1u) { uint4v nd = poll16_l2(q0);
                if (!has_canary(nd)) { d0 = nd; bad &= ~1u; } }
              if (bad & 2u) { uint4v nd = poll16_l2(q1);
                if (!has_canary(nd)) { d1 = nd; bad &= ~2u; } }
            } else {                                // fallback: IF ring (R5)
              if (bad & 1u) { if (try_esc(gbase, sid,       etag, d0)) bad &= ~1u; }
              if (bad & 2u) { if (try_esc(gbase, sid + 256, etag, d1)) bad &= ~2u; }
            }
          } while (bad);
        }
        {
          const int r = sid >> 6, blk = sid & 63;
          *(uint4v*)&hT[(size_t)r * 512 + (size_t)(blk ^ r) * 8] = d0;
        }
        {
          const int c = sid + 256;
          const int r = c >> 6, blk = c & 63;
          *(uint4v*)&hT[(size_t)r * 512 + (size_t)(blk ^ r) * 8] = d1;
        }
      }
    }
    __syncthreads();   // B1: hT staged; prev-step gates complete

    // ---- MFMAs (all waves) ----
    float4v acch = {0.f, 0.f, 0.f, 0.f};
    float4v accx = {0.f, 0.f, 0.f, 0.f};
#pragma unroll
    for (int k = 0; k < 16; ++k) {
      const int b2 = (k * 4 + quad) ^ (m & 7);
      short8 a = *(const short8*)&hT[(size_t)m * 512 + b2 * 8];
      acch = __builtin_amdgcn_mfma_f32_16x16x32_bf16(a, Bh[k], acch, 0, 0, 0);
    }
#pragma unroll
    for (int k = 0; k < 8; ++k)
      accx = __builtin_amdgcn_mfma_f32_16x16x32_bf16(xa[k], Bx[k], accx, 0, 0, 0);

    // exchange pre-activations (C-layout rows 0..7 are the valid ones)
#pragma unroll
    for (int i = 0; i < 4; ++i) {
      const int idx = (quad * 4 + i) * 16 + m;
      lds_h[wave][idx] = acch[i];
      lds_x[wave][idx] = accx[i];
    }
    // prefetch x A-frags for t+1 (in flight across the barrier)
    if (t + 1 < T_) {
      const unsigned short* xp = xb + ((size_t)(t + 1) * B_ + xrow) * D_ + quad * 8;
#pragma unroll
      for (int k = 0; k < 8; ++k) xa[k] = *(const short8*)(xp + k * 32);
    }
    __syncthreads();   // B2: lds_h/lds_x ready

    if (is_gate) {
      const int wb = s * 3;
      const unsigned tag = (unsigned)(t >> 3) & 1u;
      float* gdst = hcG + (size_t)((t & 7) * 8 + group) * 4096;
#pragma unroll
      for (int i = 0; i < 2; ++i) {
        const int row = rr * 2 + i;
        const int idx = row * 16 + col16;
        const float pr = lds_h[wb + 0][idx] + lds_x[wb + 0][idx] + bi_r;
        const float pz = lds_h[wb + 1][idx] + lds_x[wb + 1][idx] + bi_z;
        const float pn = lds_x[wb + 2][idx] + bi_n;
        const float rg = __builtin_amdgcn_rcpf(1.f + __expf(-pr));
        const float zg = __builtin_amdgcn_rcpf(1.f + __expf(-pz));
        const float an = pn + rg * (lds_h[wb + 2][idx] + bhn_c);
        const float ng = 2.f * __builtin_amdgcn_rcpf(1.f + __expf(-2.f * an)) - 1.f;
        const float hn = (1.f - zg) * ng + zg * hold[i];
        hold[i] = hn;
        const unsigned short hb = f2b(hn);
        // fast path: plain bf16 store -> shared (same-XCD) L2
        hs[((size_t)t * B_ + row0 + row) * H_ + jcol] = hb;
        // fallback path: (bf16<<16)|tag fp32 -> IF ring
        unsigned u = ((unsigned)hb << 16) | tag;
        float* p = gdst + row * 512 + jcol;
        asm volatile("global_store_dword %0, %1, off sc0 sc1"
                     :: "v"(p), "v"(u) : "memory");
      }
      // drain (hcG ring slot-reuse soundness, as proven in R5)
      asm volatile("s_waitcnt vmcnt(0)" ::: "memory");
    }
  }
}

// ---------------------------------------------------------------- ogemm -----
__global__ __launch_bounds__(256) void ogemm_kernel(
    const unsigned short* __restrict__ hs, const unsigned short* __restrict__ WoT,
    const float* __restrict__ bo, float* __restrict__ out)
{
  const int wv = threadIdx.x >> 6, lane = threadIdx.x & 63;
  const int m = lane & 15, quad = lane >> 4;
  const int rowbase = blockIdx.x * 64 + wv * 16;
  const unsigned short* ap = hs + (size_t)(rowbase + m) * H_ + quad * 8;
  float4v acc[16];
#pragma unroll
  for (int n = 0; n < 16; ++n) { float4v z = {0.f,0.f,0.f,0.f}; acc[n] = z; }
#pragma unroll
  for (int k = 0; k < 16; ++k) {
    short8 a = *(const short8*)(ap + k * 32);
#pragma unroll
    for (int n = 0; n < 16; ++n) {
      short8 b = *(const short8*)(WoT + (size_t)(n * 16 + m) * H_ + k * 32 + quad * 8);
      acc[n] = __builtin_amdgcn_mfma_f32_16x16x32_bf16(a, b, acc[n], 0, 0, 0);
    }
  }
#pragma unroll
  for (int n = 0; n < 16; ++n) {
    const int col = n * 16 + m;
    const float bias = bo[col];
#pragma unroll
    for (int i = 0; i < 4; ++i) {
      const int r = rowbase + quad * 4 + i;
      out[(size_t)r * O_ + col] = acc[n][i] + bias;
    }
  }
}

// ---------------------------------------------------------------- launch ----
extern "C" void kernel_launch(void* const* d_in, const int* in_sizes, int n_in,
                              void* d_out, int out_size, void* d_ws, size_t ws_size,
                              hipStream_t stream)
{
  const float* x   = (const float*)d_in[0];
  const float* Wi  = (const float*)d_in[1];
  const float* bi  = (const float*)d_in[2];
  const float* Wh  = (const float*)d_in[3];
  const float* bhn = (const float*)d_in[4];
  const float* Wo  = (const float*)d_in[5];
  const float* bo  = (const float*)d_in[6];
  const float* h0  = (const float*)d_in[7];
  float* out = (float*)d_out;

  char* ws = (char*)d_ws;
  unsigned short* xb  = (unsigned short*)ws;  ws += (size_t)T_ * B_ * D_ * 2;  // 33.5 MB
  unsigned short* WhT = (unsigned short*)ws;  ws += (size_t)G_ * H_ * 2;       // 1.5 MB
  unsigned short* WiT = (unsigned short*)ws;  ws += (size_t)G_ * D_ * 2;       // 0.75 MB
  unsigned short* WoT = (unsigned short*)ws;  ws += (size_t)O_ * H_ * 2;       // 0.25 MB
  unsigned short* hs  = (unsigned short*)ws;  ws += (size_t)T_ * B_ * H_ * 2;  // 67 MB
  float* hcG          = (float*)ws;                                             // 1 MB

  prep_kernel<<<4096, 256, 0, stream>>>(x, Wi, Wh, Wo, xb, WhT, WiT, WoT,
                                        (unsigned*)hs, (unsigned*)hcG);
  scan_kernel<<<128, 384, 0, stream>>>(xb, WhT, WiT, hs, hcG, bi, bhn, h0);
  ogemm_kernel<<<1024, 256, 0, stream>>>(hs, WoT, bo, out);
}

// Round 7
// 9824.338 us; speedup vs baseline: 2.1359x; 2.1359x over previous
//
#include <hip/hip_runtime.h>

// GRU: T=1024 B=64 D=256 H=512 O=256.
// Round 7: flag-less, tag-less, drain-less IF communication.
//  - h_t stored bf16 directly into hs[t] (sc0sc1 fire-and-forget). hs is a
//    virgin-address ring initialized to 0xFFFF (bf16 NaN canary, unreachable
//    from bounded GRU math) -> data is self-validating, no ABA possible.
//  - consumers poll hs[t-1] with fused-asm sc0sc1 16B loads (loads + waitcnt
//    in ONE asm block per R4's register-hazard lesson), retrying only
//    canary-bearing chunks.
//  - geometry: 32 WGs x 768 thr; 4 groups x 8 WGs; WG = 64 h-cols x 3 gates
//    (12 waves: gk=wave%3, s=wave/3). Gate waves gk==0 (4), stagers (8).
//    Halves the per-step IF broadcast vs the 64-WG layout.

#define T_ 1024
#define B_ 64
#define D_ 256
#define H_ 512
#define G_ 1536
#define O_ 256

typedef __attribute__((ext_vector_type(8))) short short8;
typedef __attribute__((ext_vector_type(4))) short short4v;
typedef __attribute__((ext_vector_type(4))) float float4v;
typedef __attribute__((ext_vector_type(4))) unsigned uint4v;

static __device__ __forceinline__ unsigned short f2b(float f) {
  unsigned u = __builtin_bit_cast(unsigned, f);
  u += 0x7fffu + ((u >> 16) & 1u);          // RNE (finite inputs)
  return (unsigned short)(u >> 16);
}

static __device__ __forceinline__ unsigned has_canary(uint4v d) {
  const unsigned m = 0xFFFFu;
  return (unsigned)(((d.x & m) == m) | ((d.x >> 16) == m) |
                    ((d.y & m) == m) | ((d.y >> 16) == m) |
                    ((d.z & m) == m) | ((d.z >> 16) == m) |
                    ((d.w & m) == m) | ((d.w >> 16) == m));
}

// 16B IF-coherent load, wait fused in-block (no use can precede the waitcnt)
static __device__ __forceinline__ uint4v poll16(const unsigned short* p) {
  uint4v d;
  asm volatile("global_load_dwordx4 %0, %1, off sc0 sc1\n\t"
               "s_waitcnt vmcnt(0)"
               : "=&v"(d) : "v"(p) : "memory");
  return d;
}

// ---------------------------------------------------------------- prep ------
__global__ __launch_bounds__(256) void prep_kernel(
    const float* __restrict__ x, const float* __restrict__ Wi,
    const float* __restrict__ Wh, const float* __restrict__ Wo,
    unsigned short* __restrict__ xb, unsigned short* __restrict__ WhT,
    unsigned short* __restrict__ WiT, unsigned short* __restrict__ WoT,
    unsigned* __restrict__ hsD)
{
  const size_t NXB = (size_t)T_ * B_ * D_;       // 16777216 shorts
  const size_t NWH = (size_t)G_ * H_;            // 786432
  const size_t NWI = (size_t)G_ * D_;            // 393216
  const size_t NWO = (size_t)O_ * H_;            // 131072
  const size_t NHS = (size_t)T_ * B_ * H_ / 2;   // 16777216 dwords (canary)
  const size_t NTOT = NXB + NWH + NWI + NWO + NHS;
  size_t i = (size_t)blockIdx.x * blockDim.x + threadIdx.x;
  const size_t stride = (size_t)gridDim.x * blockDim.x;
  for (; i < NTOT; i += stride) {
    if (i < NXB) { xb[i] = f2b(x[i]); continue; }
    size_t j = i - NXB;
    if (j < NWH) { size_t g = j >> 9, k = j & 511; WhT[j] = f2b(Wh[k * G_ + g]); continue; }
    j -= NWH;
    if (j < NWI) { size_t g = j >> 8, k = j & 255; WiT[j] = f2b(Wi[k * G_ + g]); continue; }
    j -= NWI;
    if (j < NWO) { size_t o = j >> 9, k = j & 511; WoT[j] = f2b(Wo[k * O_ + o]); continue; }
    j -= NWO;
    hsD[j] = 0xFFFFFFFFu;                        // bf16 canary pairs
  }
}

// ---------------------------------------------------------------- scan ------
// 32 WGs x 768 thr. group = wg&3 (16 batch rows), slice = wg>>2 (64 h-cols).
// wave -> (gk = wave%3, s = wave/3), s in 0..3. Wave's gate-cols =
// gk*512 + slice*64 + s*16. Gate waves: gk==0. Stagers: gk!=0 (512 thr,
// 2 x 16B chunks each of the 16KB group h tile).
__global__ __launch_bounds__(768, 1) void scan_kernel(
    const unsigned short* __restrict__ xb,
    const unsigned short* __restrict__ WhT,
    const unsigned short* __restrict__ WiT,
    unsigned short* __restrict__ hs,
    const float* __restrict__ bi,
    const float* __restrict__ bhn,
    const float* __restrict__ h0)
{
  const int wg = blockIdx.x;
  const int group = wg & 3;
  const int slice = wg >> 2;                 // 0..7
  const int tid = threadIdx.x;
  const int wave = tid >> 6;                 // 0..11
  const int lane = tid & 63;
  const int m = lane & 15;
  const int quad = lane >> 4;
  const int gk = wave % 3;
  const int s = wave / 3;                    // 0..3
  const bool is_gate = (gk == 0);
  const int sid = is_gate ? 0 : (((s * 2 + (gk - 1)) << 6) | lane);  // 0..511
  const int row0 = group * 16;
  const int jbase = slice * 64 + s * 16;     // h-col base of this wave
  const int gcol = gk * 512 + jbase + m;     // gate column for B operand

  __shared__ unsigned short hT[16 * 512];    // bf16 h tile, XOR-swizzled 16B blks
  __shared__ float lds_h[12][256];
  __shared__ float lds_x[12][256];

  // persistent B fragments (registers)
  short8 Bh[16], Bx[8];
  {
    const unsigned short* p = WhT + (size_t)gcol * H_ + quad * 8;
#pragma unroll
    for (int k = 0; k < 16; ++k) Bh[k] = *(const short8*)(p + k * 32);
    const unsigned short* q = WiT + (size_t)gcol * D_ + quad * 8;
#pragma unroll
    for (int k = 0; k < 8; ++k) Bx[k] = *(const short8*)(q + k * 32);
  }

  // gate-lane constants (gk==0 waves): col = jbase+m, rows quad*4+i
  const int jcol = jbase + m;
  const float bi_r = bi[jcol];
  const float bi_z = bi[512 + jcol];
  const float bi_n = bi[1024 + jcol];
  const float bhn_c = bhn[jcol];
  float hold[4];
#pragma unroll
  for (int i = 0; i < 4; ++i)
    hold[i] = h0[(size_t)(row0 + quad * 4 + i) * H_ + jcol];

  // x A-fragments for t=0 (batch row row0+m)
  short8 xa[8];
  {
    const unsigned short* xp = xb + (size_t)(row0 + m) * D_ + quad * 8;
#pragma unroll
    for (int k = 0; k < 8; ++k) xa[k] = *(const short8*)(xp + k * 32);
  }

  for (int t = 0; t < T_; ++t) {
    // ---- stage h_{t-1} -> hT (stager waves; chunks sid and sid+512) ----
    if (!is_gate) {
      if (t == 0) {
#pragma unroll
        for (int j = 0; j < 2; ++j) {
          const int c = sid + j * 512;
          const int r = c >> 6, col8 = c & 63;
          const float* sp = h0 + (size_t)(row0 + r) * H_ + col8 * 8;
          float4v a = *(const float4v*)sp;
          float4v b = *(const float4v*)(sp + 4);
          short8 o = { (short)f2b(a[0]), (short)f2b(a[1]),
                       (short)f2b(a[2]), (short)f2b(a[3]),
                       (short)f2b(b[0]), (short)f2b(b[1]),
                       (short)f2b(b[2]), (short)f2b(b[3]) };
          *(short8*)&hT[(size_t)r * 512 + (size_t)(col8 ^ (r & 7)) * 8] = o;
        }
      } else {
        const unsigned short* base = hs + ((size_t)(t - 1) * B_ + row0) * H_;
        const unsigned short* q0 = base + (size_t)sid * 8;
        const unsigned short* q1 = base + (size_t)(sid + 512) * 8;
        uint4v d0, d1;
        asm volatile("global_load_dwordx4 %0, %2, off sc0 sc1\n\t"
                     "global_load_dwordx4 %1, %3, off sc0 sc1\n\t"
                     "s_waitcnt vmcnt(0)"
                     : "=&v"(d0), "=&v"(d1) : "v"(q0), "v"(q1) : "memory");
        unsigned bad = has_canary(d0) | (has_canary(d1) << 1);
        while (bad) {
          __builtin_amdgcn_s_sleep(1);
          if (bad & 1u) { uint4v nd = poll16(q0);
            if (!has_canary(nd)) { d0 = nd; bad &= ~1u; } }
          if (bad & 2u) { uint4v nd = poll16(q1);
            if (!has_canary(nd)) { d1 = nd; bad &= ~2u; } }
        }
        {
          const int r = sid >> 6, col8 = sid & 63;
          *(uint4v*)&hT[(size_t)r * 512 + (size_t)(col8 ^ (r & 7)) * 8] = d0;
        }
        {
          const int c = sid + 512;
          const int r = c >> 6, col8 = c & 63;
          *(uint4v*)&hT[(size_t)r * 512 + (size_t)(col8 ^ (r & 7)) * 8] = d1;
        }
      }
    }
    __syncthreads();   // B1: hT = h_{t-1} staged; prev-step gates complete

    // ---- MFMAs (all 12 waves) ----
    float4v acch = {0.f, 0.f, 0.f, 0.f};
    float4v accx = {0.f, 0.f, 0.f, 0.f};
#pragma unroll
    for (int k = 0; k < 16; ++k) {
      const int b2 = (k * 4 + quad) ^ (m & 7);
      short8 a = *(const short8*)&hT[(size_t)m * 512 + b2 * 8];
      acch = __builtin_amdgcn_mfma_f32_16x16x32_bf16(a, Bh[k], acch, 0, 0, 0);
    }
#pragma unroll
    for (int k = 0; k < 8; ++k)
      accx = __builtin_amdgcn_mfma_f32_16x16x32_bf16(xa[k], Bx[k], accx, 0, 0, 0);

    // exchange pre-activations (C-layout: row=quad*4+i, col=m)
#pragma unroll
    for (int i = 0; i < 4; ++i) {
      const int idx = (quad * 4 + i) * 16 + m;
      lds_h[wave][idx] = acch[i];
      lds_x[wave][idx] = accx[i];
    }
    // prefetch x A-frags for t+1 (in flight across the barrier / poll)
    if (t + 1 < T_) {
      const unsigned short* xp = xb + ((size_t)(t + 1) * B_ + row0 + m) * D_ + quad * 8;
#pragma unroll
      for (int k = 0; k < 8; ++k) xa[k] = *(const short8*)(xp + k * 32);
    }
    __syncthreads();   // B2: lds_h/lds_x ready

    if (is_gate) {
      const int wb = s * 3;
#pragma unroll
      for (int i = 0; i < 4; ++i) {
        const int r = quad * 4 + i;
        const int idx = r * 16 + m;
        const float pr = lds_h[wb + 0][idx] + lds_x[wb + 0][idx] + bi_r;
        const float pz = lds_h[wb + 1][idx] + lds_x[wb + 1][idx] + bi_z;
        const float pn = lds_x[wb + 2][idx] + bi_n;
        const float rg = __builtin_amdgcn_rcpf(1.f + __expf(-pr));
        const float zg = __builtin_amdgcn_rcpf(1.f + __expf(-pz));
        const float an = pn + rg * (lds_h[wb + 2][idx] + bhn_c);
        const float ng = 2.f * __builtin_amdgcn_rcpf(1.f + __expf(-2.f * an)) - 1.f;
        const float hn = (1.f - zg) * ng + zg * hold[i];
        hold[i] = hn;
        // bf16 h -> hs[t]: sc0sc1 write-through to IF, fire-and-forget.
        // Sound: virgin address + canary init; any reader sees canary or value.
        const unsigned hb = (unsigned)f2b(hn);
        const unsigned short* p = hs + (((size_t)t * B_ + row0 + r) * H_ + jcol);
        asm volatile("global_store_short %0, %1, off sc0 sc1"
                     :: "v"(p), "v"(hb) : "memory");
      }
    }
    // stagers loop around and immediately poll hs[t]
  }
}

// ---------------------------------------------------------------- ogemm -----
__global__ __launch_bounds__(256) void ogemm_kernel(
    const unsigned short* __restrict__ hs, const unsigned short* __restrict__ WoT,
    const float* __restrict__ bo, float* __restrict__ out)
{
  const int wv = threadIdx.x >> 6, lane = threadIdx.x & 63;
  const int m = lane & 15, quad = lane >> 4;
  const int rowbase = blockIdx.x * 64 + wv * 16;
  const unsigned short* ap = hs + (size_t)(rowbase + m) * H_ + quad * 8;
  float4v acc[16];
#pragma unroll
  for (int n = 0; n < 16; ++n) { float4v z = {0.f,0.f,0.f,0.f}; acc[n] = z; }
#pragma unroll
  for (int k = 0; k < 16; ++k) {
    short8 a = *(const short8*)(ap + k * 32);
#pragma unroll
    for (int n = 0; n < 16; ++n) {
      short8 b = *(const short8*)(WoT + (size_t)(n * 16 + m) * H_ + k * 32 + quad * 8);
      acc[n] = __builtin_amdgcn_mfma_f32_16x16x32_bf16(a, b, acc[n], 0, 0, 0);
    }
  }
#pragma unroll
  for (int n = 0; n < 16; ++n) {
    const int col = n * 16 + m;
    const float bias = bo[col];
#pragma unroll
    for (int i = 0; i < 4; ++i) {
      const int r = rowbase + quad * 4 + i;
      out[(size_t)r * O_ + col] = acc[n][i] + bias;
    }
  }
}

// ---------------------------------------------------------------- launch ----
extern "C" void kernel_launch(void* const* d_in, const int* in_sizes, int n_in,
                              void* d_out, int out_size, void* d_ws, size_t ws_size,
                              hipStream_t stream)
{
  const float* x   = (const float*)d_in[0];
  const float* Wi  = (const float*)d_in[1];
  const float* bi  = (const float*)d_in[2];
  const float* Wh  = (const float*)d_in[3];
  const float* bhn = (const float*)d_in[4];
  const float* Wo  = (const float*)d_in[5];
  const float* bo  = (const float*)d_in[6];
  const float* h0  = (const float*)d_in[7];
  float* out = (float*)d_out;

  char* ws = (char*)d_ws;
  unsigned short* xb  = (unsigned short*)ws;  ws += (size_t)T_ * B_ * D_ * 2;  // 33.5 MB
  unsigned short* WhT = (unsigned short*)ws;  ws += (size_t)G_ * H_ * 2;       // 1.5 MB
  unsigned short* WiT = (unsigned short*)ws;  ws += (size_t)G_ * D_ * 2;       // 0.75 MB
  unsigned short* WoT = (unsigned short*)ws;  ws += (size_t)O_ * H_ * 2;       // 0.25 MB
  unsigned short* hs  = (unsigned short*)ws;  ws += (size_t)T_ * B_ * H_ * 2;  // 67 MB

  prep_kernel<<<4096, 256, 0, stream>>>(x, Wi, Wh, Wo, xb, WhT, WiT, WoT,
                                        (unsigned*)hs);
  scan_kernel<<<32, 768, 0, stream>>>(xb, WhT, WiT, hs, bi, bhn, h0);
  ogemm_kernel<<<1024, 256, 0, stream>>>(hs, WoT, bo, out);
}